// Round 5
// baseline (1146.760 us; speedup 1.0000x reference)
//
#include <hip/hip_runtime.h>
#include <hip/hip_fp16.h>

// Sinkhorn-Knopp on (64, 1024, 1024) fp32, 5 iterations.
// Key identity: state_k = x - U_k - V_k. With t = exp(x):
//   s_i  = sum_j t_ij * rc_j      (rc = exp(-V_prev) = 1/colsum_prev)
//   ri_i = 1/s_i = exp(-U_k)
//   colsum_j = sum_i t_ij * ri_i ; rc = 1/colsum
//   out = t * ri5_i * rc5_j
// Traffic plan: pass1 reads logits (nontemporal) and caches t=exp(x) as fp16
// (128 MiB -> fits the 256 MiB LLC). Passes 2-5 read only t (LLC-resident).
// Partials are double-buffered in out[0:8MiB] (dead until final); each pass's
// WGs redundantly reduce their batch's 16 partial slots at kernel start
// (64 KiB from L2/LLC) -> no atomics, no fences, no per-iter colred kernels.

constexpr int N = 1024;
constexpr int NQ = N / 4;  // 256 quad-units per row (float4 / H4)
constexpr int ROWS_PER_WAVE = 16;
constexpr int WAVES_PER_WG = 4;
constexpr int PASS_BLOCKS = (64 * N) / (ROWS_PER_WAVE * WAVES_PER_WG);  // 1024
constexpr int NSLOT = PASS_BLOCKS / 64;                                 // 16
constexpr int FINAL_BLOCKS = 16384;  // 16384*256 thr * 4 float4 = 64M floats

// native clang vector type: required by __builtin_nontemporal_load/store
using f4 = __attribute__((ext_vector_type(4))) float;

struct H4 {
    __half2 lo, hi;
};  // 4 halfs, 8 B

// ---------------- pass 1: read logits, write t=exp(x) fp16, partials ---------
__global__ __launch_bounds__(256) __attribute__((amdgpu_waves_per_eu(4, 4))) void
pass1_kernel(const float* __restrict__ logits, __half* __restrict__ t,
             float* __restrict__ pout) {
    __shared__ float lacc[WAVES_PER_WG * N];  // 16 KiB
    const int tid = threadIdx.x;
    const int lane = tid & 63;
    const int wid = tid >> 6;
    const int row0 = (blockIdx.x * WAVES_PER_WG + wid) * ROWS_PER_WAVE;

    float4 acc[4];
#pragma unroll
    for (int c = 0; c < 4; ++c) acc[c] = make_float4(0.f, 0.f, 0.f, 0.f);

    const f4* lb = reinterpret_cast<const f4*>(logits) + (size_t)row0 * NQ + lane;
    H4* tb = reinterpret_cast<H4*>(t) + (size_t)row0 * NQ + lane;

    auto LOADR = [&](f4* X, int r) {
#pragma unroll
        for (int c = 0; c < 4; ++c)
            X[c] = __builtin_nontemporal_load(lb + r * NQ + c * 64);  // don't pollute LLC
    };
    auto PROCESS = [&](f4* X, int r) {
        float4 sv = make_float4(0.f, 0.f, 0.f, 0.f);
#pragma unroll
        for (int c = 0; c < 4; ++c) {
            X[c].x = __expf(X[c].x); sv.x += X[c].x;
            X[c].y = __expf(X[c].y); sv.y += X[c].y;
            X[c].z = __expf(X[c].z); sv.z += X[c].z;
            X[c].w = __expf(X[c].w); sv.w += X[c].w;
        }
#pragma unroll
        for (int c = 0; c < 4; ++c) {  // cache t (normal stores -> LLC-resident)
            H4 h;
            h.lo = __floats2half2_rn(X[c].x, X[c].y);
            h.hi = __floats2half2_rn(X[c].z, X[c].w);
            tb[r * NQ + c * 64] = h;
        }
        float s = (sv.x + sv.y) + (sv.z + sv.w);
#pragma unroll
        for (int off = 32; off >= 1; off >>= 1) s += __shfl_xor(s, off);
        const float rinv = __builtin_amdgcn_rcpf(s);
#pragma unroll
        for (int c = 0; c < 4; ++c) {
            acc[c].x = fmaf(X[c].x, rinv, acc[c].x);
            acc[c].y = fmaf(X[c].y, rinv, acc[c].y);
            acc[c].z = fmaf(X[c].z, rinv, acc[c].z);
            acc[c].w = fmaf(X[c].w, rinv, acc[c].w);
        }
    };

    f4 A[4], B[4], C[4], D[4];
    LOADR(A, 0); LOADR(B, 1); LOADR(C, 2);
#pragma unroll
    for (int r = 0; r < ROWS_PER_WAVE; r += 4) {
        LOADR(D, r + 3);
        PROCESS(A, r);
        if (r + 4 < ROWS_PER_WAVE) LOADR(A, r + 4);
        PROCESS(B, r + 1);
        if (r + 5 < ROWS_PER_WAVE) LOADR(B, r + 5);
        PROCESS(C, r + 2);
        if (r + 6 < ROWS_PER_WAVE) LOADR(C, r + 6);
        PROCESS(D, r + 3);
    }

    float4* lw = reinterpret_cast<float4*>(lacc + wid * N);
#pragma unroll
    for (int c = 0; c < 4; ++c) lw[c * 64 + lane] = acc[c];
    __syncthreads();
    const int j0 = tid * 4;
    float4 s0 = *reinterpret_cast<const float4*>(lacc + 0 * N + j0);
    const float4 s1 = *reinterpret_cast<const float4*>(lacc + 1 * N + j0);
    const float4 s2 = *reinterpret_cast<const float4*>(lacc + 2 * N + j0);
    const float4 s3 = *reinterpret_cast<const float4*>(lacc + 3 * N + j0);
    s0.x += s1.x + s2.x + s3.x;
    s0.y += s1.y + s2.y + s3.y;
    s0.z += s1.z + s2.z + s3.z;
    s0.w += s1.w + s2.w + s3.w;
    *reinterpret_cast<float4*>(pout + (size_t)blockIdx.x * N + j0) = s0;
}

// ---------------- passes 2..5: read t fp16, inline rc from partials ----------
template <bool LAST>
__global__ __launch_bounds__(256) __attribute__((amdgpu_waves_per_eu(4, 4))) void
passk_kernel(const __half* __restrict__ t, const float* __restrict__ pin,
             float* __restrict__ ri, float* __restrict__ pout) {
    __shared__ float lacc[WAVES_PER_WG * N];  // 16 KiB
    __shared__ float rcs[N];                  // 4 KiB
    const int tid = threadIdx.x;
    const int lane = tid & 63;
    const int wid = tid >> 6;
    const int row0 = (blockIdx.x * WAVES_PER_WG + wid) * ROWS_PER_WAVE;
    const int b = row0 >> 10;

    const H4* tb = reinterpret_cast<const H4*>(t) + (size_t)row0 * NQ + lane;

    auto LOADR = [&](H4* X, int r) {
#pragma unroll
        for (int c = 0; c < 4; ++c) X[c] = tb[r * NQ + c * 64];
    };

    // prefetch first 3 rows so the rc-reduction overlaps the t-load latency
    H4 A[4], B[4], C[4], D[4];
    LOADR(A, 0); LOADR(B, 1); LOADR(C, 2);

    // inline column-sum reduce: this batch's 16 partial slots (64 KiB, L2/LLC-hot)
    {
        const float4* p4 =
            reinterpret_cast<const float4*>(pin) + (size_t)(b * NSLOT) * NQ + tid;
        float4 s4 = make_float4(0.f, 0.f, 0.f, 0.f);
#pragma unroll
        for (int k = 0; k < NSLOT; ++k) {
            const float4 x = p4[k * NQ];
            s4.x += x.x; s4.y += x.y; s4.z += x.z; s4.w += x.w;
        }
        float4 r4;
        r4.x = 1.0f / s4.x; r4.y = 1.0f / s4.y;
        r4.z = 1.0f / s4.z; r4.w = 1.0f / s4.w;
        reinterpret_cast<float4*>(rcs)[tid] = r4;
    }
    __syncthreads();
    float4 rc[4];
#pragma unroll
    for (int c = 0; c < 4; ++c) rc[c] = reinterpret_cast<const float4*>(rcs)[c * 64 + lane];

    float4 acc[4];
#pragma unroll
    for (int c = 0; c < 4; ++c) acc[c] = make_float4(0.f, 0.f, 0.f, 0.f);

    auto PROCESS = [&](H4* X, int r) {
        float4 tf[4];
        float4 sv = make_float4(0.f, 0.f, 0.f, 0.f);
#pragma unroll
        for (int c = 0; c < 4; ++c) {
            const float2 l = __half22float2(X[c].lo);
            const float2 h = __half22float2(X[c].hi);
            tf[c] = make_float4(l.x, l.y, h.x, h.y);
            sv.x = fmaf(tf[c].x, rc[c].x, sv.x);
            sv.y = fmaf(tf[c].y, rc[c].y, sv.y);
            sv.z = fmaf(tf[c].z, rc[c].z, sv.z);
            sv.w = fmaf(tf[c].w, rc[c].w, sv.w);
        }
        float s = (sv.x + sv.y) + (sv.z + sv.w);
#pragma unroll
        for (int off = 32; off >= 1; off >>= 1) s += __shfl_xor(s, off);
        const float rinv = __builtin_amdgcn_rcpf(s);
        if constexpr (LAST) {
            if (lane == 0) ri[row0 + r] = rinv;  // exp(-u5), consumed by final
        }
#pragma unroll
        for (int c = 0; c < 4; ++c) {
            acc[c].x = fmaf(tf[c].x, rinv, acc[c].x);
            acc[c].y = fmaf(tf[c].y, rinv, acc[c].y);
            acc[c].z = fmaf(tf[c].z, rinv, acc[c].z);
            acc[c].w = fmaf(tf[c].w, rinv, acc[c].w);
        }
    };

#pragma unroll
    for (int r = 0; r < ROWS_PER_WAVE; r += 4) {
        LOADR(D, r + 3);
        PROCESS(A, r);
        if (r + 4 < ROWS_PER_WAVE) LOADR(A, r + 4);
        PROCESS(B, r + 1);
        if (r + 5 < ROWS_PER_WAVE) LOADR(B, r + 5);
        PROCESS(C, r + 2);
        if (r + 6 < ROWS_PER_WAVE) LOADR(C, r + 6);
        PROCESS(D, r + 3);
    }

    float4* lw = reinterpret_cast<float4*>(lacc + wid * N);
#pragma unroll
    for (int c = 0; c < 4; ++c) lw[c * 64 + lane] = acc[c];
    __syncthreads();
    const int j0 = tid * 4;
    float4 s0 = *reinterpret_cast<const float4*>(lacc + 0 * N + j0);
    const float4 s1 = *reinterpret_cast<const float4*>(lacc + 1 * N + j0);
    const float4 s2 = *reinterpret_cast<const float4*>(lacc + 2 * N + j0);
    const float4 s3 = *reinterpret_cast<const float4*>(lacc + 3 * N + j0);
    s0.x += s1.x + s2.x + s3.x;
    s0.y += s1.y + s2.y + s3.y;
    s0.z += s1.z + s2.z + s3.z;
    s0.w += s1.w + s2.w + s3.w;
    *reinterpret_cast<float4*>(pout + (size_t)blockIdx.x * N + j0) = s0;
}

// ---------------- colred after pass 5: rc5 = 1/colsum5 ----------------------
__global__ __launch_bounds__(256) void colred_kernel(const float* __restrict__ pin,
                                                     float* __restrict__ rc5) {
    const int tt = blockIdx.x * 256 + threadIdx.x;  // 16384 threads, 1 float4 each
    const int e = tt << 2;
    const int b = e >> 10;
    const int j = e & 1023;
    const float4* p =
        reinterpret_cast<const float4*>(pin) + (size_t)(b * NSLOT) * NQ + (j >> 2);
    float4 s = make_float4(0.f, 0.f, 0.f, 0.f);
#pragma unroll
    for (int k = 0; k < NSLOT; ++k) {
        const float4 x = p[k * NQ];
        s.x += x.x; s.y += x.y; s.z += x.z; s.w += x.w;
    }
    float4 o;
    o.x = 1.0f / s.x; o.y = 1.0f / s.y; o.z = 1.0f / s.z; o.w = 1.0f / s.w;
    *reinterpret_cast<float4*>(rc5 + e) = o;
}

// ---------------- final: out = t * ri_i * rc5_j ------------------------------
template <bool USE_T>
__global__ __launch_bounds__(256) void final_kernel(
    const float* __restrict__ logits, const __half* __restrict__ t,
    const float* __restrict__ ri, const float* __restrict__ rc5,
    float* __restrict__ out) {
    const int g0 = blockIdx.x * 256 + threadIdx.x;
#pragma unroll
    for (int p = 0; p < 4; ++p) {
        const int g = g0 + p * (FINAL_BLOCKS * 256);  // float4 index < 16777216
        const int e = g << 2;
        const int r = e >> 10;
        const int jc = e & 1023;
        const int b = r >> 10;
        const float rr = ri[r];
        const float4 rv = *reinterpret_cast<const float4*>(rc5 + (b << 10) + jc);
        f4 o;
        if constexpr (USE_T) {
            const H4 th = reinterpret_cast<const H4*>(t)[(size_t)r * NQ + (jc >> 2)];
            const float2 l = __half22float2(th.lo);
            const float2 h = __half22float2(th.hi);
            o.x = l.x * rr * rv.x;
            o.y = l.y * rr * rv.y;
            o.z = h.x * rr * rv.z;
            o.w = h.y * rr * rv.w;
        } else {
            const f4 x = __builtin_nontemporal_load(
                reinterpret_cast<const f4*>(logits) + g);
            o.x = __expf(x.x) * rr * rv.x;
            o.y = __expf(x.y) * rr * rv.y;
            o.z = __expf(x.z) * rr * rv.z;
            o.w = __expf(x.w) * rr * rv.w;
        }
        __builtin_nontemporal_store(o, reinterpret_cast<f4*>(out) + g);
    }
}

extern "C" void kernel_launch(void* const* d_in, const int* in_sizes, int n_in,
                              void* d_out, int out_size, void* d_ws, size_t ws_size,
                              hipStream_t stream) {
    const float* logits = (const float*)d_in[0];
    float* out = (float*)d_out;
    float* ws = (float*)d_ws;
    float* ri = ws;            // 65536 floats (1/s per row)
    float* rc5 = ws + 65536;   // 65536 floats -> 512 KiB base workspace
    // partials: double-buffered in out[0 : 8 MiB] (dead until final overwrites)
    float* p0 = out;
    float* p1 = out + (1 << 20);
    // t (fp16, 128 MiB): workspace if it fits, else out's upper half (then the
    // final kernel reads logits instead of t -> no read/write overlap either way)
    const bool t_in_ws = ws_size >= (size_t)512 * 1024 + (size_t)128 * 1024 * 1024;
    __half* t = t_in_ws ? reinterpret_cast<__half*>(ws + 2 * 65536)
                        : reinterpret_cast<__half*>(out + (1 << 25));  // +128 MiB

    pass1_kernel<<<PASS_BLOCKS, 256, 0, stream>>>(logits, t, p0);
    passk_kernel<false><<<PASS_BLOCKS, 256, 0, stream>>>(t, p0, ri, p1);
    passk_kernel<false><<<PASS_BLOCKS, 256, 0, stream>>>(t, p1, ri, p0);
    passk_kernel<false><<<PASS_BLOCKS, 256, 0, stream>>>(t, p0, ri, p1);
    passk_kernel<true><<<PASS_BLOCKS, 256, 0, stream>>>(t, p1, ri, p0);
    colred_kernel<<<64, 256, 0, stream>>>(p0, rc5);
    if (t_in_ws) {
        final_kernel<true><<<FINAL_BLOCKS, 256, 0, stream>>>(logits, t, ri, rc5, out);
    } else {
        final_kernel<false><<<FINAL_BLOCKS, 256, 0, stream>>>(logits, t, ri, rc5, out);
    }
}

// Round 8
// 702.565 us; speedup vs baseline: 1.6322x; 1.6322x over previous
//
#include <hip/hip_runtime.h>

// Sinkhorn-Knopp, log-space, on (64, 1024, 1024) fp32, 5 iterations.
// Carried state: rc[j] = 1/colsum[j] (= exp(-v)); u written only on last pass.
// Pass k (one fused read of logits):
//   t[i,j] = exp(logits[i,j])            (|logits| <= ~5.6 for N(0,1): safe fp32)
//   s[i]   = sum_j t[i,j] * rc_{k-1}[j]  (wave-local row reduce)
//   partial colsum[j] = sum_i t[i,j]/s[i] -> per-WG slot, coalesced stores, NO atomics
// colred: rc_k = 1/sum_slots partial  (v = log(sum) on last pass)
// Final: out = exp(logits - u5 - v5).
// partials live in out[0:4MiB] (dead until final overwrites). Workspace 768 KiB.
//
// Register discipline (the round-1/round-5 lesson): NO occupancy attributes —
// they squeeze VGPR to 64 and kill the load pipeline. Instead the pipeline is
// 2-deep by construction (A/B, ~64 live data VGPRs + temps ≈ 90) so the
// allocator naturally lands under the 128-VGPR occupancy step -> 4 waves/SIMD
// -> all 1024 WGs co-resident in a single round.

constexpr int N = 1024;
constexpr int NQ = N / 4;  // float4 units per row
constexpr int ROWS_PER_WAVE = 16;
constexpr int WAVES_PER_WG = 4;
constexpr int PASS_BLOCKS = (64 * N) / (ROWS_PER_WAVE * WAVES_PER_WG);  // 1024
constexpr int NSLOT = PASS_BLOCKS / 64;                                 // 16
constexpr int FINAL_BLOCKS = 16384;  // 16384*256 thr * 4 float4 = 64M floats

template <bool PASS1, bool LAST>
__global__ __launch_bounds__(256) void sinkhorn_pass_kernel(
    const float* __restrict__ logits, const float* __restrict__ rcprev,
    float* __restrict__ u, float* __restrict__ partials) {
    __shared__ float lacc[WAVES_PER_WG * N];  // 16 KiB

    const int tid = threadIdx.x;
    const int lane = tid & 63;
    const int wid = tid >> 6;
    const int row0 = (blockIdx.x * WAVES_PER_WG + wid) * ROWS_PER_WAVE;
    const int b = row0 >> 10;

    // rc = 1/colsum_prev, cached per wave: rc[c] covers j = c*256 + lane*4 + {0..3}
    float4 rc[4];
    if constexpr (!PASS1) {
        const float4* cb = reinterpret_cast<const float4*>(rcprev + (b << 10));
#pragma unroll
        for (int c = 0; c < 4; ++c) rc[c] = cb[c * 64 + lane];
    }

    float4 acc[4];
#pragma unroll
    for (int c = 0; c < 4; ++c) acc[c] = make_float4(0.f, 0.f, 0.f, 0.f);

    const float4* lb =
        reinterpret_cast<const float4*>(logits) + (size_t)row0 * NQ + lane;

    auto LOADR = [&](float4* X, int r) {
#pragma unroll
        for (int c = 0; c < 4; ++c) X[c] = lb[r * NQ + c * 64];
    };

    auto PROCESS = [&](float4* X, int r) {
        float4 sv = make_float4(0.f, 0.f, 0.f, 0.f);
#pragma unroll
        for (int c = 0; c < 4; ++c) {
            X[c].x = __expf(X[c].x);
            X[c].y = __expf(X[c].y);
            X[c].z = __expf(X[c].z);
            X[c].w = __expf(X[c].w);
            if constexpr (PASS1) {
                sv.x += X[c].x;
                sv.y += X[c].y;
                sv.z += X[c].z;
                sv.w += X[c].w;
            } else {
                sv.x = fmaf(X[c].x, rc[c].x, sv.x);
                sv.y = fmaf(X[c].y, rc[c].y, sv.y);
                sv.z = fmaf(X[c].z, rc[c].z, sv.z);
                sv.w = fmaf(X[c].w, rc[c].w, sv.w);
            }
        }
        float s = (sv.x + sv.y) + (sv.z + sv.w);
#pragma unroll
        for (int off = 32; off >= 1; off >>= 1) s += __shfl_xor(s, off);
        if constexpr (LAST) {
            if (lane == 0) u[row0 + r] = __logf(s);  // only pass 5's u is consumed
        }
        const float rinv = __builtin_amdgcn_rcpf(s);
#pragma unroll
        for (int c = 0; c < 4; ++c) {
            acc[c].x = fmaf(X[c].x, rinv, acc[c].x);
            acc[c].y = fmaf(X[c].y, rinv, acc[c].y);
            acc[c].z = fmaf(X[c].z, rinv, acc[c].z);
            acc[c].w = fmaf(X[c].w, rinv, acc[c].w);
        }
    };

    // 2-deep software pipeline: one row (4 KiB) always in flight behind the
    // row being processed; fits ~90 VGPR so occupancy stays at 4 waves/SIMD.
    float4 A[4], B[4];
    LOADR(A, 0);
#pragma unroll
    for (int r = 0; r < ROWS_PER_WAVE; r += 2) {
        LOADR(B, r + 1);
        PROCESS(A, r);
        if (r + 2 < ROWS_PER_WAVE) LOADR(A, r + 2);
        PROCESS(B, r + 1);
    }

    // wave partials -> LDS, reduce across the 4 waves, coalesced store to this
    // WG's private partial slot (slot = blockIdx.x). No atomics.
    float4* lw = reinterpret_cast<float4*>(lacc + wid * N);
#pragma unroll
    for (int c = 0; c < 4; ++c) lw[c * 64 + lane] = acc[c];
    __syncthreads();

    const int j0 = tid * 4;  // 256 threads x 4 = 1024 columns
    float4 s0 = *reinterpret_cast<const float4*>(lacc + 0 * N + j0);
    const float4 s1 = *reinterpret_cast<const float4*>(lacc + 1 * N + j0);
    const float4 s2 = *reinterpret_cast<const float4*>(lacc + 2 * N + j0);
    const float4 s3 = *reinterpret_cast<const float4*>(lacc + 3 * N + j0);
    s0.x += s1.x + s2.x + s3.x;
    s0.y += s1.y + s2.y + s3.y;
    s0.z += s1.z + s2.z + s3.z;
    s0.w += s1.w + s2.w + s3.w;
    *reinterpret_cast<float4*>(partials + (size_t)blockIdx.x * N + j0) = s0;
}

template <bool LAST>
__global__ __launch_bounds__(256) void colred_kernel(const float* __restrict__ partials,
                                                     float* __restrict__ out) {
    // reduce the NSLOT per-WG partial vectors of each batch.
    // out = LAST ? v = log(colsum) : rc = 1/colsum
    const int t = blockIdx.x * 256 + threadIdx.x;  // 16384 threads, one float4 each
    const int e = t << 2;                          // element index (b*1024 + j)
    const int b = e >> 10;
    const int j = e & 1023;
    const float4* p =
        reinterpret_cast<const float4*>(partials + (size_t)(b * NSLOT) * N + j);
    float4 s = make_float4(0.f, 0.f, 0.f, 0.f);
#pragma unroll
    for (int k = 0; k < NSLOT; ++k) {
        const float4 x = p[k * NQ];
        s.x += x.x;
        s.y += x.y;
        s.z += x.z;
        s.w += x.w;
    }
    float4 o;
    if constexpr (LAST) {
        o.x = __logf(s.x);
        o.y = __logf(s.y);
        o.z = __logf(s.z);
        o.w = __logf(s.w);
    } else {
        o.x = 1.0f / s.x;
        o.y = 1.0f / s.y;
        o.z = 1.0f / s.z;
        o.w = 1.0f / s.w;
    }
    *reinterpret_cast<float4*>(out + e) = o;
}

__global__ __launch_bounds__(256) void final_kernel(const float* __restrict__ logits,
                                                    const float* __restrict__ u,
                                                    const float* __restrict__ v,
                                                    float* __restrict__ out) {
    const int g0 = blockIdx.x * 256 + threadIdx.x;
#pragma unroll
    for (int p = 0; p < 4; ++p) {
        const int g = g0 + p * (FINAL_BLOCKS * 256);  // float4 index < 16777216
        const int e = g << 2;                         // element index < 2^27
        const int r = e >> 10;
        const int jc = e & 1023;
        const int b = r >> 10;
        const float ur = u[r];
        const float4 vv = *reinterpret_cast<const float4*>(v + (b << 10) + jc);
        const float4 x = *reinterpret_cast<const float4*>(logits + (size_t)e);
        float4 o;
        o.x = __expf(x.x - ur - vv.x);
        o.y = __expf(x.y - ur - vv.y);
        o.z = __expf(x.z - ur - vv.z);
        o.w = __expf(x.w - ur - vv.w);
        *reinterpret_cast<float4*>(out + (size_t)e) = o;
    }
}

extern "C" void kernel_launch(void* const* d_in, const int* in_sizes, int n_in,
                              void* d_out, int out_size, void* d_ws, size_t ws_size,
                              hipStream_t stream) {
    const float* logits = (const float*)d_in[0];
    float* out = (float*)d_out;
    float* ws = (float*)d_ws;
    float* u = ws;               // 65536 floats
    float* v = ws + 65536;       // 65536 floats
    float* rc = ws + 2 * 65536;  // 65536 floats -> 768 KiB workspace total
    // partials scratch lives in the OUTPUT buffer (4 MiB of 256 MiB); out is
    // written only by final_kernel after all passes, so it is dead space now.
    float* partials = out;

    sinkhorn_pass_kernel<true, false>
        <<<PASS_BLOCKS, 256, 0, stream>>>(logits, rc, u, partials);
    colred_kernel<false><<<64, 256, 0, stream>>>(partials, rc);
    for (int it = 1; it < 4; ++it) {
        sinkhorn_pass_kernel<false, false>
            <<<PASS_BLOCKS, 256, 0, stream>>>(logits, rc, u, partials);
        colred_kernel<false><<<64, 256, 0, stream>>>(partials, rc);
    }
    sinkhorn_pass_kernel<false, true>
        <<<PASS_BLOCKS, 256, 0, stream>>>(logits, rc, u, partials);
    colred_kernel<true><<<64, 256, 0, stream>>>(partials, v);
    final_kernel<<<FINAL_BLOCKS, 256, 0, stream>>>(logits, u, v, out);
}